// Round 2
// baseline (744.014 us; speedup 1.0000x reference)
//
#include <hip/hip_runtime.h>
#include <hip/hip_bf16.h>
#include <stdint.h>

// GQA attention w/ KV cache. B=4, Sq=4, H=32, Hkv=8, g=4, D=Dv=128, Smax=8192.
// Dtype of Q/K/V/out resolved AT RUNTIME by sniffing K's bit patterns (bf16
// pairs have exponent bits at [14:7]; fp32 has uniform mantissa bits there).
#define B_    4
#define SQ    4
#define H_    32
#define HKV   8
#define G_    4
#define D_    128
#define SMAX  8192
#define ROWS  16            // SQ * G_ q-rows per (b,hkv)
#define BH    (B_ * HKV)    // 32
#define SCALE 0.08838834764831845f  // 1/sqrt(128)
#define MAXSPLITS 16

__device__ __forceinline__ void unpack8(const uint4& u, float* f) {
  f[0] = __uint_as_float(u.x << 16);
  f[1] = __uint_as_float(u.x & 0xffff0000u);
  f[2] = __uint_as_float(u.y << 16);
  f[3] = __uint_as_float(u.y & 0xffff0000u);
  f[4] = __uint_as_float(u.z << 16);
  f[5] = __uint_as_float(u.z & 0xffff0000u);
  f[6] = __uint_as_float(u.w << 16);
  f[7] = __uint_as_float(u.w & 0xffff0000u);
}

template<bool BF16>
__device__ __forceinline__ void load8(const void* base, size_t eoff, float* f) {
  if constexpr (BF16) {
    uint4 u = *(const uint4*)((const __hip_bfloat16*)base + eoff);
    unpack8(u, f);
  } else {
    const float4* p = (const float4*)((const float*)base + eoff);
    const float4 a = p[0], b = p[1];
    f[0]=a.x; f[1]=a.y; f[2]=a.z; f[3]=a.w;
    f[4]=b.x; f[5]=b.y; f[6]=b.z; f[7]=b.w;
  }
}

// Classify K's dtype: sample 1024 uint32 words. For packed bf16 pairs, the low
// element's exponent field sits at bits [14:7] and is ~127 for N(0,1) data ->
// window hit-rate ~100%. For fp32, bits [14:7] are mantissa bits -> ~20%.
__global__ __launch_bounds__(256)
void sniff_dtype(const uint32_t* __restrict__ Kw, int* __restrict__ flag) {
  __shared__ int s_cnt;
  const int t = threadIdx.x;
  if (t == 0) s_cnt = 0;
  __syncthreads();
  int local = 0;
#pragma unroll
  for (int i = 0; i < 4; ++i) {
    const uint32_t w = Kw[t * 4 + i];
    const uint32_t e = (w >> 7) & 0xFFu;
    local += (e >= 100u && e <= 150u) ? 1 : 0;
  }
  atomicAdd(&s_cnt, local);
  __syncthreads();
  if (t == 0) flag[0] = (s_cnt > 700) ? 1 : 0;   // 1 = bf16, 0 = fp32
}

template<bool BF16>
__global__ __launch_bounds__(256)
void attn_partial(const void* __restrict__ Q, const void* __restrict__ K,
                  const void* __restrict__ V, const int* __restrict__ lens,
                  const int* __restrict__ flag, int splits, int chunk,
                  float2* __restrict__ stats, float* __restrict__ acc_out) {
  if (flag[0] != (BF16 ? 1 : 0)) return;   // wrong-dtype variant: no-op

  const int split = blockIdx.x;
  const int bh    = blockIdx.y;
  const int b     = bh >> 3;
  const int hkv   = bh & 7;
  const int t     = threadIdx.x;
  const int r     = t >> 4;      // q-row 0..15
  const int c     = t & 15;      // 8-wide slice of D
  const int m     = r >> 2;      // query pos 0..3
  const int gq    = r & 3;
  const int h     = hkv * G_ + gq;

  int len = lens[b];
  if (len > SMAX) len = SMAX;
  if (len < 0)    len = 0;
  const int lim = len - SQ + m;            // valid keys: j <= lim

  const int j0   = split * chunk;
  const int jend = min(j0 + chunk, len);
  const int sidx = (bh * splits + split) * ROWS + r;

  if (j0 >= jend) {
    if (c == 0) stats[sidx] = make_float2(-INFINITY, 0.0f);
    return;
  }

  float qf[8];
  load8<BF16>(Q, (size_t)(((b * SQ + m) * H_ + h) * D_) + c * 8, qf);

  const size_t kv0     = ((size_t)b * SMAX * HKV + hkv) * D_ + c * 8;
  const size_t kstride = (size_t)HKV * D_;

  float m_run = -INFINITY;
  float l_run = 0.0f;
  float acc[8] = {0.f,0.f,0.f,0.f,0.f,0.f,0.f,0.f};

  for (int j = j0; j < jend; ++j) {
    float kf[8];
    load8<BF16>(K, kv0 + (size_t)j * kstride, kf);
    float p = 0.0f;
#pragma unroll
    for (int i = 0; i < 8; ++i) p = fmaf(qf[i], kf[i], p);
    p += __shfl_xor(p, 1, 16);
    p += __shfl_xor(p, 2, 16);
    p += __shfl_xor(p, 4, 16);
    p += __shfl_xor(p, 8, 16);
    const float s = p * SCALE;
    const bool valid = (j <= lim);

    float m_new = valid ? fmaxf(m_run, s) : m_run;
    float alpha, pw;
    if (m_new == -INFINITY) {
      alpha = 1.0f;
      pw    = 0.0f;
    } else {
      alpha = __expf(m_run - m_new);
      pw    = valid ? __expf(s - m_new) : 0.0f;
    }

    float vf[8];
    load8<BF16>(V, kv0 + (size_t)j * kstride, vf);

    l_run = l_run * alpha + pw;
    m_run = m_new;
#pragma unroll
    for (int i = 0; i < 8; ++i) acc[i] = fmaf(acc[i], alpha, pw * vf[i]);
  }

  if (c == 0) stats[sidx] = make_float2(m_run, l_run);
  float* ap = acc_out + (size_t)sidx * D_ + c * 8;
  *(float4*)(ap)     = make_float4(acc[0], acc[1], acc[2], acc[3]);
  *(float4*)(ap + 4) = make_float4(acc[4], acc[5], acc[6], acc[7]);
}

template<bool BF16>
__global__ __launch_bounds__(256)
void attn_reduce(const float2* __restrict__ stats,
                 const float* __restrict__ acc_in,
                 const int* __restrict__ flag, int splits,
                 void* __restrict__ out) {
  if (flag[0] != (BF16 ? 1 : 0)) return;

  const int bh  = blockIdx.x;
  const int b   = bh >> 3;
  const int hkv = bh & 7;
  const int t   = threadIdx.x;
  const int r   = t >> 4;
  const int c   = t & 15;
  const int m   = r >> 2;
  const int gq  = r & 3;
  const int h   = hkv * G_ + gq;

  __shared__ float2 sst[MAXSPLITS * ROWS];
  if (t < splits * ROWS) sst[t] = stats[bh * (splits * ROWS) + t];
  __syncthreads();

  float M = -INFINITY;
  for (int s2 = 0; s2 < splits; ++s2) M = fmaxf(M, sst[s2 * ROWS + r].x);

  float L = 0.0f;
  float o[8] = {0.f,0.f,0.f,0.f,0.f,0.f,0.f,0.f};
  for (int s2 = 0; s2 < splits; ++s2) {
    const float2 ml = sst[s2 * ROWS + r];
    if (ml.y > 0.0f) {                     // also rejects NaN partials
      const float w = __expf(ml.x - M);
      L += w * ml.y;
      const float4* ap = (const float4*)(acc_in +
          ((size_t)(bh * splits + s2) * ROWS + r) * D_ + c * 8);
      const float4 a0 = ap[0];
      const float4 a1 = ap[1];
      o[0] += w * a0.x; o[1] += w * a0.y; o[2] += w * a0.z; o[3] += w * a0.w;
      o[4] += w * a1.x; o[5] += w * a1.y; o[6] += w * a1.z; o[7] += w * a1.w;
    }
  }
  const float inv = (L > 0.0f) ? (1.0f / L) : 0.0f;
  const size_t oo = ((size_t)(b * SQ + m) * H_ + h) * D_ + c * 8;
  if constexpr (BF16) {
    __hip_bfloat16* op = (__hip_bfloat16*)out + oo;
#pragma unroll
    for (int i = 0; i < 8; ++i) op[i] = __float2bfloat16(o[i] * inv);
  } else {
    float* op = (float*)out + oo;
    *(float4*)(op)     = make_float4(o[0]*inv, o[1]*inv, o[2]*inv, o[3]*inv);
    *(float4*)(op + 4) = make_float4(o[4]*inv, o[5]*inv, o[6]*inv, o[7]*inv);
  }
}

extern "C" void kernel_launch(void* const* d_in, const int* in_sizes, int n_in,
                              void* d_out, int out_size, void* d_ws, size_t ws_size,
                              hipStream_t stream) {
  const void* Q   = d_in[0];
  const void* K   = d_in[1];
  const void* V   = d_in[2];
  const int* lens = (const int*)d_in[3];

  // Workspace: [flag:256B][stats: S*4096B][acc: S*262144B]
  const size_t per_split = (size_t)BH * ROWS * sizeof(float2)
                         + (size_t)BH * ROWS * D_ * sizeof(float);  // 266240
  int S = 1;
  if (ws_size > 256 + per_split)
    S = (int)((ws_size - 256) / per_split);
  if (S < 1) S = 1;
  if (S > MAXSPLITS) S = MAXSPLITS;
  const int chunk = (SMAX + S - 1) / S;

  int*    flag  = (int*)d_ws;
  float2* stats = (float2*)((char*)d_ws + 256);
  float*  acc   = (float*)((char*)d_ws + 256 + (size_t)S * BH * ROWS * sizeof(float2));

  sniff_dtype<<<1, 256, 0, stream>>>((const uint32_t*)K, flag);

  dim3 g1(S, BH);
  attn_partial<true ><<<g1, 256, 0, stream>>>(Q, K, V, lens, flag, S, chunk, stats, acc);
  attn_partial<false><<<g1, 256, 0, stream>>>(Q, K, V, lens, flag, S, chunk, stats, acc);
  attn_reduce<true ><<<BH, 256, 0, stream>>>(stats, acc, flag, S, d_out);
  attn_reduce<false><<<BH, 256, 0, stream>>>(stats, acc, flag, S, d_out);
}

// Round 4
// 418.083 us; speedup vs baseline: 1.7796x; 1.7796x over previous
//
#include <hip/hip_runtime.h>
#include <hip/hip_bf16.h>
#include <stdint.h>

// GQA attention w/ KV cache. B=4, Sq=4, H=32, Hkv=8, g=4, D=Dv=128, Smax=8192.
// Device dtype of Q/K/V/out is NOT stable across harness runs (R2 run was bf16
// by FETCH_SIZE evidence; R1/R3 hardcoded-bf16 runs produced the fp32-misread
// all-zeros signature). So: runtime dtype sniffer + gated dual-dtype kernels.
// DO NOT REMOVE THE SNIFFER.
#define B_    4
#define SQ    4
#define H_    32
#define HKV   8
#define G_    4
#define D_    128
#define SMAX  8192
#define ROWS  16            // SQ * G_ q-rows per (b,hkv)
#define BH    (B_ * HKV)    // 32
#define SCALE 0.08838834764831845f  // 1/sqrt(128)
#define MAXSPLITS 32

__device__ __forceinline__ void unpack8(const uint4& u, float* f) {
  f[0] = __uint_as_float(u.x << 16);
  f[1] = __uint_as_float(u.x & 0xffff0000u);
  f[2] = __uint_as_float(u.y << 16);
  f[3] = __uint_as_float(u.y & 0xffff0000u);
  f[4] = __uint_as_float(u.z << 16);
  f[5] = __uint_as_float(u.z & 0xffff0000u);
  f[6] = __uint_as_float(u.w << 16);
  f[7] = __uint_as_float(u.w & 0xffff0000u);
}

// Classify K's dtype from 1024 sampled words: packed-bf16 words carry the low
// element's exponent at bits[14:7] (~127 for N(0,1) -> ~100% window hits);
// fp32 words have mantissa bits there (~20% hits).
__global__ __launch_bounds__(256)
void fa4_sniff(const uint32_t* __restrict__ Kw, int* __restrict__ flag) {
  __shared__ int s_cnt;
  const int t = threadIdx.x;
  if (t == 0) s_cnt = 0;
  __syncthreads();
  int local = 0;
#pragma unroll
  for (int i = 0; i < 4; ++i) {
    const uint32_t w = Kw[t * 4 + i];
    const uint32_t e = (w >> 7) & 0xFFu;
    local += (e >= 100u && e <= 150u) ? 1 : 0;
  }
  atomicAdd(&s_cnt, local);
  __syncthreads();
  if (t == 0) flag[0] = (s_cnt > 700) ? 1 : 0;   // 1 = bf16, 0 = fp32
}

template<bool BF16>
__device__ __forceinline__ void loadrow(const void* base, size_t eoff, float* f) {
  if constexpr (BF16) {
    uint4 u = *(const uint4*)((const __hip_bfloat16*)base + eoff);
    unpack8(u, f);
  } else {
    const float4* p = (const float4*)((const float*)base + eoff);
    const float4 a = p[0], b = p[1];
    f[0]=a.x; f[1]=a.y; f[2]=a.z; f[3]=a.w;
    f[4]=b.x; f[5]=b.y; f[6]=b.z; f[7]=b.w;
  }
}

template<bool BF16>
__global__ __launch_bounds__(256, 3)
void fa4_partial(const void* __restrict__ Q, const void* __restrict__ K,
                 const void* __restrict__ V, const int* __restrict__ lens,
                 const int* __restrict__ flag, int splits, int chunk,
                 float2* __restrict__ stats, float* __restrict__ acc_out) {
  if (flag[0] != (BF16 ? 1 : 0)) return;   // wrong-dtype variant: no-op

  constexpr int KBATCH = BF16 ? 8 : 4;

  const int split = blockIdx.x;
  const int bh    = blockIdx.y;
  const int b     = bh >> 3;
  const int hkv   = bh & 7;
  const int t     = threadIdx.x;
  const int r     = t >> 4;      // q-row 0..15
  const int c     = t & 15;      // 8-wide slice of D
  const int m     = r >> 2;      // query pos 0..3
  const int gq    = r & 3;
  const int h     = hkv * G_ + gq;

  int len = lens[b];
  if (len > SMAX) len = SMAX;
  if (len < 0)    len = 0;
  const int lim = len - SQ + m;            // valid keys: j <= lim

  const int j0   = split * chunk;
  const int jend = min(j0 + chunk, len);
  const int sidx = (bh * splits + split) * ROWS + r;

  if (j0 >= jend) {
    if (c == 0) stats[sidx] = make_float2(-INFINITY, 0.0f);
    return;
  }

  float qf[8];
  loadrow<BF16>(Q, (size_t)(((b * SQ + m) * H_ + h) * D_) + c * 8, qf);

  const size_t kv0     = ((size_t)b * SMAX * HKV + hkv) * D_ + c * 8;
  const size_t kstride = (size_t)HKV * D_;
  const int    jmax    = jend - 1;

  float m_run = -INFINITY;
  float l_run = 0.0f;
  float acc[8] = {0.f,0.f,0.f,0.f,0.f,0.f,0.f,0.f};

  for (int j = j0; j < jend; j += KBATCH) {
    // Stage K and V rows for KBATCH keys: independent loads, latency amortized.
    float kf[KBATCH][8], vf[KBATCH][8];
#pragma unroll
    for (int kb = 0; kb < KBATCH; ++kb) {
      const size_t off = kv0 + (size_t)min(j + kb, jmax) * kstride;
      loadrow<BF16>(K, off, kf[kb]);
      loadrow<BF16>(V, off, vf[kb]);
    }

    // Scores: KBATCH independent dot+shuffle-reduce chains (pipeline).
    float sc[KBATCH];
#pragma unroll
    for (int kb = 0; kb < KBATCH; ++kb) {
      float p = qf[0] * kf[kb][0];
#pragma unroll
      for (int i = 1; i < 8; ++i) p = fmaf(qf[i], kf[kb][i], p);
      p += __shfl_xor(p, 1, 16);
      p += __shfl_xor(p, 2, 16);
      p += __shfl_xor(p, 4, 16);
      p += __shfl_xor(p, 8, 16);
      const int jj = j + kb;
      sc[kb] = (jj < jend && jj <= lim) ? p * SCALE : -INFINITY;
    }

    // Batched online softmax: one rescale per KBATCH keys.
    float bm = sc[0];
#pragma unroll
    for (int kb = 1; kb < KBATCH; ++kb) bm = fmaxf(bm, sc[kb]);
    const float m_new = fmaxf(m_run, bm);
    if (m_new != -INFINITY) {
      const float alpha = __expf(m_run - m_new);   // m_run=-inf -> 0
      float pw[KBATCH];
      float lsum = 0.0f;
#pragma unroll
      for (int kb = 0; kb < KBATCH; ++kb) {
        pw[kb] = __expf(sc[kb] - m_new);           // sc=-inf -> 0
        lsum  += pw[kb];
      }
      l_run = fmaf(l_run, alpha, lsum);
      m_run = m_new;
#pragma unroll
      for (int i = 0; i < 8; ++i) acc[i] *= alpha;
#pragma unroll
      for (int kb = 0; kb < KBATCH; ++kb)
#pragma unroll
        for (int i = 0; i < 8; ++i) acc[i] = fmaf(pw[kb], vf[kb][i], acc[i]);
    }
  }

  if (c == 0) stats[sidx] = make_float2(m_run, l_run);
  float* ap = acc_out + (size_t)sidx * D_ + c * 8;
  *(float4*)(ap)     = make_float4(acc[0], acc[1], acc[2], acc[3]);
  *(float4*)(ap + 4) = make_float4(acc[4], acc[5], acc[6], acc[7]);
}

template<bool BF16>
__global__ __launch_bounds__(256)
void fa4_reduce(const float2* __restrict__ stats,
                const float* __restrict__ acc_in,
                const int* __restrict__ flag, int splits,
                void* __restrict__ out) {
  if (flag[0] != (BF16 ? 1 : 0)) return;

  const int bh  = blockIdx.x;
  const int b   = bh >> 3;
  const int hkv = bh & 7;
  const int t   = threadIdx.x;
  const int r   = t >> 4;
  const int c   = t & 15;
  const int m   = r >> 2;
  const int gq  = r & 3;
  const int h   = hkv * G_ + gq;

  __shared__ float2 sst[MAXSPLITS * ROWS];
  for (int i = t; i < splits * ROWS; i += 256)
    sst[i] = stats[bh * (splits * ROWS) + i];
  __syncthreads();

  float M = -INFINITY;
  for (int s2 = 0; s2 < splits; ++s2) M = fmaxf(M, sst[s2 * ROWS + r].x);

  float L = 0.0f;
  float o[8] = {0.f,0.f,0.f,0.f,0.f,0.f,0.f,0.f};
  for (int s2 = 0; s2 < splits; ++s2) {
    const float2 ml = sst[s2 * ROWS + r];
    if (ml.y > 0.0f) {                     // also rejects NaN partials
      const float w = __expf(ml.x - M);
      L += w * ml.y;
      const float4* ap = (const float4*)(acc_in +
          ((size_t)(bh * splits + s2) * ROWS + r) * D_ + c * 8);
      const float4 a0 = ap[0];
      const float4 a1 = ap[1];
      o[0] += w * a0.x; o[1] += w * a0.y; o[2] += w * a0.z; o[3] += w * a0.w;
      o[4] += w * a1.x; o[5] += w * a1.y; o[6] += w * a1.z; o[7] += w * a1.w;
    }
  }
  const float inv = (L > 0.0f) ? (1.0f / L) : 0.0f;
  const size_t oo = ((size_t)(b * SQ + m) * H_ + h) * D_ + c * 8;
  if constexpr (BF16) {
    __hip_bfloat16* op = (__hip_bfloat16*)out + oo;
#pragma unroll
    for (int i = 0; i < 8; ++i) op[i] = __float2bfloat16(o[i] * inv);
  } else {
    float* op = (float*)out + oo;
    *(float4*)(op)     = make_float4(o[0]*inv, o[1]*inv, o[2]*inv, o[3]*inv);
    *(float4*)(op + 4) = make_float4(o[4]*inv, o[5]*inv, o[6]*inv, o[7]*inv);
  }
}

extern "C" void kernel_launch(void* const* d_in, const int* in_sizes, int n_in,
                              void* d_out, int out_size, void* d_ws, size_t ws_size,
                              hipStream_t stream) {
  const void* Q   = d_in[0];
  const void* K   = d_in[1];
  const void* V   = d_in[2];
  const int* lens = (const int*)d_in[3];

  // Workspace: [flag:256B][stats: S*BH*ROWS*8B][acc: S*BH*ROWS*D*4B]
  const size_t per_split = (size_t)BH * ROWS * sizeof(float2)
                         + (size_t)BH * ROWS * D_ * sizeof(float);  // 266240 B
  int S = 1;
  if (ws_size > 256 + per_split)
    S = (int)((ws_size - 256) / per_split);
  if (S < 1) S = 1;
  if (S > MAXSPLITS) S = MAXSPLITS;
  const int chunk = (SMAX + S - 1) / S;

  int*    flag  = (int*)d_ws;
  float2* stats = (float2*)((char*)d_ws + 256);
  float*  acc   = (float*)((char*)d_ws + 256 + (size_t)S * BH * ROWS * sizeof(float2));

  fa4_sniff<<<1, 256, 0, stream>>>((const uint32_t*)K, flag);

  dim3 g1(S, BH);
  fa4_partial<true ><<<g1, 256, 0, stream>>>(Q, K, V, lens, flag, S, chunk, stats, acc);
  fa4_partial<false><<<g1, 256, 0, stream>>>(Q, K, V, lens, flag, S, chunk, stats, acc);
  fa4_reduce<true ><<<BH, 256, 0, stream>>>(stats, acc, flag, S, d_out);
  fa4_reduce<false><<<BH, 256, 0, stream>>>(stats, acc, flag, S, d_out);
}